// Round 1
// baseline (471.822 us; speedup 1.0000x reference)
//
#include <hip/hip_runtime.h>

// Problem constants
constexpr int QN  = 10001;   // questions (Q+1)
constexpr int CN  = 201;     // concepts rows in E_c (C+1)
constexpr int DD  = 64;      // D
constexpr int GG  = 192;     // 3H
constexpr int BB  = 512;     // batch
constexpr int TT  = 200;     // seq len
constexpr int MQD = 132;     // qd hidden
constexpr int MDC = 32;      // dc hidden

__device__ __forceinline__ float sigm(float x) { return 1.f / (1.f + __expf(-x)); }
__device__ __forceinline__ float tanh_fast(float x) { return 1.f - 2.f / (1.f + __expf(2.f * x)); }

// ---------------------------------------------------------------------------
// Kernel 1: tiny precomputed tables.
//   T_c [201][192]  = W_ih[:,64:128]  @ E_c[r]
//   T_it[101][192]  = W_ih[:,192:256] @ E_it[r]
//   T_ut[101][192]  = W_ih[:,256:320] @ (W_fuse[:,0:64]   @ E_ut[r])
//   T_nh[101][192]  = W_ih[:,256:320] @ (W_fuse[:,64:128] @ E_nh[r])
//   T_na[101][192]  = W_ih[:,256:320] @ (W_fuse[:,128:192]@ E_nh[r])
//   bias0[192]      = b_ih + W_ih[:,256:320] @ b_fuse
//   Vcorr[192]      = rowsum of W_ih[:,128:192]
// ---------------------------------------------------------------------------
__global__ void k_tables(const float* __restrict__ E_c, const float* __restrict__ E_it,
                         const float* __restrict__ E_ut, const float* __restrict__ E_nh,
                         const float* __restrict__ W_fuse, const float* __restrict__ b_fuse,
                         const float* __restrict__ W_ih, const float* __restrict__ b_ih,
                         float* __restrict__ T_c, float* __restrict__ T_it,
                         float* __restrict__ T_ut, float* __restrict__ T_nh, float* __restrict__ T_na,
                         float* __restrict__ bias0, float* __restrict__ Vcorr)
{
    int blk = blockIdx.x, j = threadIdx.x; // 192 threads
    __shared__ float s_e[64];
    __shared__ float s_t[64];

    if (blk < 201) {
        if (j < 64) s_e[j] = E_c[blk * 64 + j];
        __syncthreads();
        float a = 0.f;
        #pragma unroll
        for (int k = 0; k < 64; k++) a += W_ih[j * 320 + 64 + k] * s_e[k];
        T_c[blk * 192 + j] = a;
    } else if (blk < 302) {
        int r = blk - 201;
        if (j < 64) s_e[j] = E_it[r * 64 + j];
        __syncthreads();
        float a = 0.f;
        #pragma unroll
        for (int k = 0; k < 64; k++) a += W_ih[j * 320 + 192 + k] * s_e[k];
        T_it[r * 192 + j] = a;
    } else if (blk < 605) {
        int which = (blk - 302) / 101;
        int r     = (blk - 302) % 101;
        const float* E = (which == 0) ? E_ut : E_nh;
        int fofs = which * 64;
        if (j < 64) s_e[j] = E[r * 64 + j];
        __syncthreads();
        if (j < 64) {
            float a = 0.f;
            #pragma unroll
            for (int d = 0; d < 64; d++) a += W_fuse[j * 192 + fofs + d] * s_e[d];
            s_t[j] = a;
        }
        __syncthreads();
        float a = 0.f;
        #pragma unroll
        for (int e = 0; e < 64; e++) a += W_ih[j * 320 + 256 + e] * s_t[e];
        float* outp = (which == 0) ? T_ut : ((which == 1) ? T_nh : T_na);
        outp[r * 192 + j] = a;
    } else {
        float a = b_ih[j];
        #pragma unroll
        for (int e = 0; e < 64; e++) a += W_ih[j * 320 + 256 + e] * b_fuse[e];
        bias0[j] = a;
        float v = 0.f;
        #pragma unroll
        for (int k = 0; k < 64; k++) v += W_ih[j * 320 + 128 + k];
        Vcorr[j] = v;
    }
}

// ---------------------------------------------------------------------------
// Kernel 2: per-question precompute (10001 blocks x 192 threads).
//   hidden = relu(qd_W1 @ qe + b1)
//   raw_k  = sigmoid(qd_W2[c_k]·hidden + b2[c_k]);  rel_k = raw_k*mask_k
//   w_k    = rel_k / (sum rel + 1e-6)
//   Xq[q]  = W_ih[:,0:64] @ qe + sum_k w_k * T_c[c_k]
//   disc[q], qdsum[q] (dedup'd), wdk[q][k] (dedup flags)
// ---------------------------------------------------------------------------
__global__ void k_perq(const float* __restrict__ E_q, const float* __restrict__ W_ih,
                       const float* __restrict__ qd_W1, const float* __restrict__ qd_b1,
                       const float* __restrict__ qd_W2, const float* __restrict__ qd_b2,
                       const float* __restrict__ dc_W1, const float* __restrict__ dc_b1,
                       const float* __restrict__ dc_W2, const float* __restrict__ dc_b2,
                       const int* __restrict__ q2c, const int* __restrict__ q2cm,
                       const float* __restrict__ T_c,
                       float* __restrict__ Xq, float* __restrict__ disc,
                       float* __restrict__ qds, float* __restrict__ wdk)
{
    int q = blockIdx.x, tid = threadIdx.x;
    __shared__ float s_qe[64], s_hid[132], s_dch[32], s_raw[4], s_rel[4], s_w[4];
    __shared__ int s_c[4], s_m[4];

    if (tid < 64) s_qe[tid] = E_q[q * 64 + tid];
    if (tid >= 64 && tid < 68) { s_c[tid - 64] = q2c[q * 4 + tid - 64]; s_m[tid - 64] = q2cm[q * 4 + tid - 64]; }
    __syncthreads();

    if (tid < 132) {
        float a = qd_b1[tid];
        const float* w = qd_W1 + tid * 64;
        #pragma unroll
        for (int k = 0; k < 64; k++) a += w[k] * s_qe[k];
        s_hid[tid] = fmaxf(a, 0.f);
    } else if (tid < 164) {
        int i = tid - 132;
        float a = dc_b1[i];
        const float* w = dc_W1 + i * 64;
        #pragma unroll
        for (int k = 0; k < 64; k++) a += w[k] * s_qe[k];
        s_dch[i] = fmaxf(a, 0.f);
    }
    __syncthreads();

    if (tid < 4) {
        int c = s_c[tid];
        float a = qd_b2[c];
        const float* w = qd_W2 + c * 132;
        for (int m = 0; m < 132; m++) a += w[m] * s_hid[m];
        float raw = sigm(a);
        s_raw[tid] = raw;
        s_rel[tid] = raw * (float)s_m[tid];
    } else if (tid == 100) {
        float a = dc_b2[0];
        #pragma unroll
        for (int i = 0; i < 32; i++) a += dc_W2[i] * s_dch[i];
        disc[q] = sigm(a) * 10.f;
    }
    __syncthreads();

    if (tid == 0) {
        float sr = s_rel[0] + s_rel[1] + s_rel[2] + s_rel[3] + 1e-6f;
        float qsum = 0.f;
        for (int k = 0; k < 4; k++) {
            s_w[k] = s_rel[k] / sr;
            float wd = 0.f;
            if (s_m[k]) {
                bool dup = false;
                for (int jj = 0; jj < k; jj++)
                    if (s_m[jj] && s_c[jj] == s_c[k]) dup = true;
                if (!dup) { wd = 1.f; qsum += s_raw[k]; }
            }
            wdk[q * 4 + k] = wd;
        }
        qds[q] = qsum;
    }
    __syncthreads();

    {
        float a = 0.f;
        const float* w = W_ih + tid * 320;
        #pragma unroll
        for (int k = 0; k < 64; k++) a += w[k] * s_qe[k];
        #pragma unroll
        for (int k = 0; k < 4; k++) a += s_w[k] * T_c[s_c[k] * 192 + tid];
        Xq[q * 192 + tid] = a;
    }
}

// ---------------------------------------------------------------------------
// Kernel 3: GRU scan, one wave per batch sample. W_hh rows in registers,
// h broadcast via LDS. xp assembled on the fly from gathered table rows,
// prefetched one step ahead.
// ---------------------------------------------------------------------------
__global__ void __launch_bounds__(64, 1) k_gru(
    const float* __restrict__ W_hh, const float* __restrict__ b_hh,
    const float* __restrict__ Xq, const float* __restrict__ Tit, const float* __restrict__ Tut,
    const float* __restrict__ Tnh, const float* __restrict__ Tna,
    const float* __restrict__ b0, const float* __restrict__ vc,
    const int* __restrict__ qseq, const int* __restrict__ cseq, const int* __restrict__ itseq,
    const int* __restrict__ utseq, const int* __restrict__ nhseq, const int* __restrict__ naseq,
    float* __restrict__ latent)
{
    int b = blockIdx.x, i = threadIdx.x;
    __shared__ float s_h[64];

    float4 wr[16], wz[16], wn[16];
    {
        const float4* p0 = (const float4*)(W_hh + i * 64);
        const float4* p1 = (const float4*)(W_hh + (64 + i) * 64);
        const float4* p2 = (const float4*)(W_hh + (128 + i) * 64);
        #pragma unroll
        for (int k = 0; k < 16; k++) { wr[k] = p0[k]; wz[k] = p1[k]; wn[k] = p2[k]; }
    }
    float bhr = b_hh[i], bhz = b_hh[64 + i], bhn = b_hh[128 + i];
    float b0r = b0[i],   b0z = b0[64 + i],   b0n = b0[128 + i];
    float vcr = vc[i],   vcz = vc[64 + i],   vcn = vc[128 + i];

    s_h[i] = 0.f;
    float hi = 0.f;
    __syncthreads();

    const int base = b * TT;
    float g[15];
    float cof;
    {
        int q = qseq[base], it = itseq[base], ut = utseq[base], nh = nhseq[base], na = naseq[base];
        cof = (float)cseq[base];
        const float* xq = Xq + q * 192;  const float* ti = Tit + it * 192;
        const float* tu = Tut + ut * 192; const float* tn = Tnh + nh * 192;
        const float* ta = Tna + na * 192;
        g[0] = xq[i];  g[1] = xq[64 + i];  g[2] = xq[128 + i];
        g[3] = ti[i];  g[4] = ti[64 + i];  g[5] = ti[128 + i];
        g[6] = tu[i];  g[7] = tu[64 + i];  g[8] = tu[128 + i];
        g[9] = tn[i];  g[10] = tn[64 + i]; g[11] = tn[128 + i];
        g[12] = ta[i]; g[13] = ta[64 + i]; g[14] = ta[128 + i];
    }

    for (int t = 0; t < TT; t++) {
        float ng[15];
        float ncof = 0.f;
        if (t + 1 < TT) {  // prefetch next step's gathers
            int q = qseq[base + t + 1], it = itseq[base + t + 1], ut = utseq[base + t + 1];
            int nh = nhseq[base + t + 1], na = naseq[base + t + 1];
            ncof = (float)cseq[base + t + 1];
            const float* xq = Xq + q * 192;  const float* ti = Tit + it * 192;
            const float* tu = Tut + ut * 192; const float* tn = Tnh + nh * 192;
            const float* ta = Tna + na * 192;
            ng[0] = xq[i];  ng[1] = xq[64 + i];  ng[2] = xq[128 + i];
            ng[3] = ti[i];  ng[4] = ti[64 + i];  ng[5] = ti[128 + i];
            ng[6] = tu[i];  ng[7] = tu[64 + i];  ng[8] = tu[128 + i];
            ng[9] = tn[i];  ng[10] = tn[64 + i]; ng[11] = tn[128 + i];
            ng[12] = ta[i]; ng[13] = ta[64 + i]; ng[14] = ta[128 + i];
        }

        // gh = W_hh @ h + b_hh (three rows per lane), h broadcast from LDS
        float ar = bhr, az = bhz, an = bhn;
        const float4* h4 = (const float4*)s_h;
        #pragma unroll
        for (int k = 0; k < 16; k++) {
            float4 h = h4[k];
            ar += wr[k].x * h.x + wr[k].y * h.y + wr[k].z * h.z + wr[k].w * h.w;
            az += wz[k].x * h.x + wz[k].y * h.y + wz[k].z * h.z + wz[k].w * h.w;
            an += wn[k].x * h.x + wn[k].y * h.y + wn[k].z * h.z + wn[k].w * h.w;
        }
        __syncthreads();  // all lanes done reading s_h

        float xr = b0r + cof * vcr + g[0] + g[3] + g[6] + g[9]  + g[12];
        float xz = b0z + cof * vcz + g[1] + g[4] + g[7] + g[10] + g[13];
        float xn = b0n + cof * vcn + g[2] + g[5] + g[8] + g[11] + g[14];

        float r = sigm(xr + ar);
        float z = sigm(xz + az);
        float n = tanh_fast(xn + r * an);
        hi = (1.f - z) * n + z * hi;

        latent[(base + t) * 64 + i] = hi;
        s_h[i] = hi;
        __syncthreads();  // write visible before next iteration's reads

        if (t + 1 < TT) {
            #pragma unroll
            for (int k = 0; k < 15; k++) g[k] = ng[k];
            cof = ncof;
        }
    }
}

// ---------------------------------------------------------------------------
// Kernel 4: readout, one thread per output token.
//   hidden = relu(la_W1 @ lat + b1)  (weights wave-uniform -> scalar loads)
//   ua_sum = sum_dedup sigmoid(la_W2[c]·hidden + b2[c])
//   out    = sigmoid(disc*(ua_sum - qdsum)/(qdsum+1e-6))
// ---------------------------------------------------------------------------
__global__ void __launch_bounds__(256) k_final(
    const float* __restrict__ latent, const int* __restrict__ qseq,
    const float* __restrict__ la_W1, const float* __restrict__ la_b1,
    const float* __restrict__ la_W2, const float* __restrict__ la_b2,
    const int* __restrict__ q2c,
    const float* __restrict__ disc, const float* __restrict__ qds,
    const float* __restrict__ wdk, float* __restrict__ out)
{
    int o = blockIdx.x * blockDim.x + threadIdx.x;
    if (o >= BB * (TT - 1)) return;
    int b = o / (TT - 1), t = o - b * (TT - 1);

    const float* lat = latent + (size_t)(b * TT + t) * 64;
    float l[64];
    #pragma unroll
    for (int k4 = 0; k4 < 16; k4++) {
        float4 v = ((const float4*)lat)[k4];
        l[k4 * 4] = v.x; l[k4 * 4 + 1] = v.y; l[k4 * 4 + 2] = v.z; l[k4 * 4 + 3] = v.w;
    }

    int q = qseq[b * TT + t + 1];
    int c0 = q2c[q * 4], c1 = q2c[q * 4 + 1], c2 = q2c[q * 4 + 2], c3 = q2c[q * 4 + 3];

    float u0 = 0.f, u1 = 0.f, u2 = 0.f, u3 = 0.f;
    for (int m = 0; m < 132; m++) {
        float a = la_b1[m];
        const float* w = la_W1 + m * 64;
        #pragma unroll
        for (int k = 0; k < 64; k++) a += w[k] * l[k];
        float hm = fmaxf(a, 0.f);
        u0 += la_W2[c0 * 132 + m] * hm;
        u1 += la_W2[c1 * 132 + m] * hm;
        u2 += la_W2[c2 * 132 + m] * hm;
        u3 += la_W2[c3 * 132 + m] * hm;
    }

    float w0 = wdk[q * 4], w1 = wdk[q * 4 + 1], w2 = wdk[q * 4 + 2], w3 = wdk[q * 4 + 3];
    float us = w0 * sigm(u0 + la_b2[c0]) + w1 * sigm(u1 + la_b2[c1])
             + w2 * sigm(u2 + la_b2[c2]) + w3 * sigm(u3 + la_b2[c3]);
    float qs = qds[q];
    float y = disc[q] * (us - qs) / (qs + 1e-6f);
    out[o] = sigm(y);
}

// ---------------------------------------------------------------------------
extern "C" void kernel_launch(void* const* d_in, const int* in_sizes, int n_in,
                              void* d_out, int out_size, void* d_ws, size_t ws_size,
                              hipStream_t stream)
{
    const float* E_q    = (const float*)d_in[0];
    const float* E_c    = (const float*)d_in[1];
    const float* E_it   = (const float*)d_in[2];
    const float* E_ut   = (const float*)d_in[3];
    const float* E_nh   = (const float*)d_in[4];
    const float* W_fuse = (const float*)d_in[5];
    const float* b_fuse = (const float*)d_in[6];
    const float* W_ih   = (const float*)d_in[7];
    const float* b_ih   = (const float*)d_in[8];
    const float* W_hh   = (const float*)d_in[9];
    const float* b_hh   = (const float*)d_in[10];
    const float* qd_W1  = (const float*)d_in[11];
    const float* qd_b1  = (const float*)d_in[12];
    const float* qd_W2  = (const float*)d_in[13];
    const float* qd_b2  = (const float*)d_in[14];
    const float* la_W1  = (const float*)d_in[15];
    const float* la_b1  = (const float*)d_in[16];
    const float* la_W2  = (const float*)d_in[17];
    const float* la_b2  = (const float*)d_in[18];
    const float* dc_W1  = (const float*)d_in[19];
    const float* dc_b1  = (const float*)d_in[20];
    const float* dc_W2  = (const float*)d_in[21];
    const float* dc_b2  = (const float*)d_in[22];

    // setup_inputs() dict order puts Q_table LAST (index 31). Defensively handle
    // the reference-signature order too (Q_table at 23): detect by element count.
    int off = (in_sizes[23] == QN * 200) ? 1 : 0;
    const int* qseq  = (const int*)d_in[23 + off];
    const int* cseq  = (const int*)d_in[24 + off];
    const int* itseq = (const int*)d_in[25 + off];
    const int* utseq = (const int*)d_in[26 + off];
    const int* nhseq = (const int*)d_in[27 + off];
    const int* naseq = (const int*)d_in[28 + off];
    const int* q2c   = (const int*)d_in[29 + off];
    const int* q2cm  = (const int*)d_in[30 + off];
    // Q_table itself is not needed: it is exactly the 0/1 dedup'd concept
    // indicator derived from q2c_table/q2c_mask.

    float* ws = (float*)d_ws;
    size_t o = 0;
    float* T_c  = ws + o; o += (size_t)201 * 192;
    float* Tit  = ws + o; o += (size_t)101 * 192;
    float* Tut  = ws + o; o += (size_t)101 * 192;
    float* Tnh  = ws + o; o += (size_t)101 * 192;
    float* Tna  = ws + o; o += (size_t)101 * 192;
    float* b0   = ws + o; o += 192;
    float* vc   = ws + o; o += 192;
    float* Xq   = ws + o; o += (size_t)QN * 192;
    float* disc = ws + o; o += QN;
    float* qds  = ws + o; o += QN;
    float* wdk  = ws + o; o += (size_t)QN * 4;
    float* latent = ws + o; o += (size_t)BB * TT * 64;

    float* outp = (float*)d_out;

    k_tables<<<606, 192, 0, stream>>>(E_c, E_it, E_ut, E_nh, W_fuse, b_fuse, W_ih, b_ih,
                                      T_c, Tit, Tut, Tnh, Tna, b0, vc);
    k_perq<<<QN, 192, 0, stream>>>(E_q, W_ih, qd_W1, qd_b1, qd_W2, qd_b2,
                                   dc_W1, dc_b1, dc_W2, dc_b2, q2c, q2cm, T_c,
                                   Xq, disc, qds, wdk);
    k_gru<<<BB, 64, 0, stream>>>(W_hh, b_hh, Xq, Tit, Tut, Tnh, Tna, b0, vc,
                                 qseq, cseq, itseq, utseq, nhseq, naseq, latent);
    k_final<<<(BB * (TT - 1) + 255) / 256, 256, 0, stream>>>(latent, qseq, la_W1, la_b1,
                                                             la_W2, la_b2, q2c, disc, qds, wdk, outp);
}

// Round 2
// 403.349 us; speedup vs baseline: 1.1698x; 1.1698x over previous
//
#include <hip/hip_runtime.h>

// Problem constants
constexpr int QN  = 10001;   // questions (Q+1)
constexpr int BB  = 512;     // batch
constexpr int TT  = 200;     // seq len

__device__ __forceinline__ float sigm(float x) { return 1.f / (1.f + __expf(-x)); }
__device__ __forceinline__ float tanh_fast(float x) { return 1.f - 2.f / (1.f + __expf(2.f * x)); }

// ---------------------------------------------------------------------------
// Kernel 1: tiny precomputed tables.
//   T_c [201][192]  = W_ih[:,64:128]  @ E_c[r]
//   T_it[101][192]  = W_ih[:,192:256] @ E_it[r]
//   T_ut[101][192]  = W_ih[:,256:320] @ (W_fuse[:,0:64]   @ E_ut[r])
//   T_nh[101][192]  = W_ih[:,256:320] @ (W_fuse[:,64:128] @ E_nh[r])
//   T_na[101][192]  = W_ih[:,256:320] @ (W_fuse[:,128:192]@ E_nh[r])
//   bias0[192]      = b_ih + W_ih[:,256:320] @ b_fuse
//   Vcorr[192]      = rowsum of W_ih[:,128:192]
// ---------------------------------------------------------------------------
__global__ void k_tables(const float* __restrict__ E_c, const float* __restrict__ E_it,
                         const float* __restrict__ E_ut, const float* __restrict__ E_nh,
                         const float* __restrict__ W_fuse, const float* __restrict__ b_fuse,
                         const float* __restrict__ W_ih, const float* __restrict__ b_ih,
                         float* __restrict__ T_c, float* __restrict__ T_it,
                         float* __restrict__ T_ut, float* __restrict__ T_nh, float* __restrict__ T_na,
                         float* __restrict__ bias0, float* __restrict__ Vcorr)
{
    int blk = blockIdx.x, j = threadIdx.x; // 192 threads
    __shared__ float s_e[64];
    __shared__ float s_t[64];

    if (blk < 201) {
        if (j < 64) s_e[j] = E_c[blk * 64 + j];
        __syncthreads();
        float a = 0.f;
        #pragma unroll
        for (int k = 0; k < 64; k++) a += W_ih[j * 320 + 64 + k] * s_e[k];
        T_c[blk * 192 + j] = a;
    } else if (blk < 302) {
        int r = blk - 201;
        if (j < 64) s_e[j] = E_it[r * 64 + j];
        __syncthreads();
        float a = 0.f;
        #pragma unroll
        for (int k = 0; k < 64; k++) a += W_ih[j * 320 + 192 + k] * s_e[k];
        T_it[r * 192 + j] = a;
    } else if (blk < 605) {
        int which = (blk - 302) / 101;
        int r     = (blk - 302) % 101;
        const float* E = (which == 0) ? E_ut : E_nh;
        int fofs = which * 64;
        if (j < 64) s_e[j] = E[r * 64 + j];
        __syncthreads();
        if (j < 64) {
            float a = 0.f;
            #pragma unroll
            for (int d = 0; d < 64; d++) a += W_fuse[j * 192 + fofs + d] * s_e[d];
            s_t[j] = a;
        }
        __syncthreads();
        float a = 0.f;
        #pragma unroll
        for (int e = 0; e < 64; e++) a += W_ih[j * 320 + 256 + e] * s_t[e];
        float* outp = (which == 0) ? T_ut : ((which == 1) ? T_nh : T_na);
        outp[r * 192 + j] = a;
    } else {
        float a = b_ih[j];
        #pragma unroll
        for (int e = 0; e < 64; e++) a += W_ih[j * 320 + 256 + e] * b_fuse[e];
        bias0[j] = a;
        float v = 0.f;
        #pragma unroll
        for (int k = 0; k < 64; k++) v += W_ih[j * 320 + 128 + k];
        Vcorr[j] = v;
    }
}

// ---------------------------------------------------------------------------
// Kernel 2: per-question precompute (10001 blocks x 192 threads).
// ---------------------------------------------------------------------------
__global__ void k_perq(const float* __restrict__ E_q, const float* __restrict__ W_ih,
                       const float* __restrict__ qd_W1, const float* __restrict__ qd_b1,
                       const float* __restrict__ qd_W2, const float* __restrict__ qd_b2,
                       const float* __restrict__ dc_W1, const float* __restrict__ dc_b1,
                       const float* __restrict__ dc_W2, const float* __restrict__ dc_b2,
                       const int* __restrict__ q2c, const int* __restrict__ q2cm,
                       const float* __restrict__ T_c,
                       float* __restrict__ Xq, float* __restrict__ disc,
                       float* __restrict__ qds, float* __restrict__ wdk)
{
    int q = blockIdx.x, tid = threadIdx.x;
    __shared__ float s_qe[64], s_hid[132], s_dch[32], s_raw[4], s_rel[4], s_w[4];
    __shared__ int s_c[4], s_m[4];

    if (tid < 64) s_qe[tid] = E_q[q * 64 + tid];
    if (tid >= 64 && tid < 68) { s_c[tid - 64] = q2c[q * 4 + tid - 64]; s_m[tid - 64] = q2cm[q * 4 + tid - 64]; }
    __syncthreads();

    if (tid < 132) {
        float a = qd_b1[tid];
        const float* w = qd_W1 + tid * 64;
        #pragma unroll
        for (int k = 0; k < 64; k++) a += w[k] * s_qe[k];
        s_hid[tid] = fmaxf(a, 0.f);
    } else if (tid < 164) {
        int i = tid - 132;
        float a = dc_b1[i];
        const float* w = dc_W1 + i * 64;
        #pragma unroll
        for (int k = 0; k < 64; k++) a += w[k] * s_qe[k];
        s_dch[i] = fmaxf(a, 0.f);
    }
    __syncthreads();

    // concept dots: 4 groups of 32 lanes (waves 0,1), shuffle-reduced
    if (tid < 128) {
        int g = tid >> 5, l = tid & 31;
        int c = s_c[g];
        float a = 0.f;
        for (int m = l; m < 132; m += 32) a += qd_W2[c * 132 + m] * s_hid[m];
        #pragma unroll
        for (int off = 16; off; off >>= 1) a += __shfl_xor(a, off, 32);
        if (l == 0) {
            float raw = sigm(a + qd_b2[c]);
            s_raw[g] = raw;
            s_rel[g] = raw * (float)s_m[g];
        }
    } else if (tid < 160) {
        // disc dot on lanes 0..31 of wave 2
        int l = tid - 128;
        float a = dc_W2[l] * s_dch[l];
        #pragma unroll
        for (int off = 16; off; off >>= 1) a += __shfl_xor(a, off, 32);
        if (l == 0) disc[q] = sigm(a + dc_b2[0]) * 10.f;
    }
    __syncthreads();

    if (tid == 0) {
        float sr = s_rel[0] + s_rel[1] + s_rel[2] + s_rel[3] + 1e-6f;
        float qsum = 0.f;
        for (int k = 0; k < 4; k++) {
            s_w[k] = s_rel[k] / sr;
            float wd = 0.f;
            if (s_m[k]) {
                bool dup = false;
                for (int jj = 0; jj < k; jj++)
                    if (s_m[jj] && s_c[jj] == s_c[k]) dup = true;
                if (!dup) { wd = 1.f; qsum += s_raw[k]; }
            }
            wdk[q * 4 + k] = wd;
        }
        qds[q] = qsum;
    }
    __syncthreads();

    {
        float a = 0.f;
        const float* w = W_ih + tid * 320;
        #pragma unroll
        for (int k = 0; k < 64; k++) a += w[k] * s_qe[k];
        #pragma unroll
        for (int k = 0; k < 4; k++) a += s_w[k] * T_c[s_c[k] * 192 + tid];
        Xq[q * 192 + tid] = a;
    }
}

// ---------------------------------------------------------------------------
// Kernel 3: GRU scan, 192 threads (3 waves) per sample. Lane j owns gate-row j
// of W_hh (64 VGPRs), h broadcast via LDS, indices staged in LDS, table
// gathers prefetched one step ahead (5 loads/lane).
// ---------------------------------------------------------------------------
__global__ void __launch_bounds__(192) k_gru(
    const float* __restrict__ W_hh, const float* __restrict__ b_hh,
    const float* __restrict__ Xq, const float* __restrict__ Tit, const float* __restrict__ Tut,
    const float* __restrict__ Tnh, const float* __restrict__ Tna,
    const float* __restrict__ b0, const float* __restrict__ vc,
    const int* __restrict__ qseq, const int* __restrict__ cseq, const int* __restrict__ itseq,
    const int* __restrict__ utseq, const int* __restrict__ nhseq, const int* __restrict__ naseq,
    float* __restrict__ latent)
{
    int b = blockIdx.x, j = threadIdx.x;
    __shared__ float s_h[64];
    __shared__ float s_a[192];
    __shared__ float s_x[192];
    __shared__ int s_q[TT], s_c[TT], s_it[TT], s_ut[TT], s_nh[TT], s_na[TT];

    const int base = b * TT;
    for (int i = j; i < TT; i += 192) {
        s_q[i]  = qseq[base + i];
        s_c[i]  = cseq[base + i];
        s_it[i] = itseq[base + i];
        s_ut[i] = utseq[base + i];
        s_nh[i] = nhseq[base + i];
        s_na[i] = naseq[base + i];
    }

    // lane j's gate row of W_hh: 16 float4 = 64 VGPRs (fits, no spill)
    float4 w4[16];
    {
        const float4* wp = (const float4*)(W_hh + j * 64);
        #pragma unroll
        for (int k = 0; k < 16; k++) w4[k] = wp[k];
    }
    float bh = b_hh[j], b0j = b0[j], vcj = vc[j];

    if (j < 64) s_h[j] = 0.f;
    float hi = 0.f;
    __syncthreads();  // covers s_idx + s_h init

    // t=0 gathers
    float g0, g1, g2, g3, g4, cof;
    {
        int q = s_q[0], it = s_it[0], ut = s_ut[0], nh = s_nh[0], na = s_na[0];
        cof = (float)s_c[0];
        g0 = Xq[q * 192 + j];  g1 = Tit[it * 192 + j]; g2 = Tut[ut * 192 + j];
        g3 = Tnh[nh * 192 + j]; g4 = Tna[na * 192 + j];
    }

    for (int t = 0; t < TT; t++) {
        // prefetch t+1 gathers (indices from LDS -> no global index chain)
        float n0 = 0.f, n1 = 0.f, n2 = 0.f, n3 = 0.f, n4 = 0.f, ncof = 0.f;
        if (t + 1 < TT) {
            int q = s_q[t + 1], it = s_it[t + 1], ut = s_ut[t + 1];
            int nh = s_nh[t + 1], na = s_na[t + 1];
            ncof = (float)s_c[t + 1];
            n0 = Xq[q * 192 + j];  n1 = Tit[it * 192 + j]; n2 = Tut[ut * 192 + j];
            n3 = Tnh[nh * 192 + j]; n4 = Tna[na * 192 + j];
        }

        // a[j] = W_hh[j,:] . h + b_hh[j]  (h broadcast from LDS, 4 accumulators)
        float a0 = 0.f, a1 = 0.f, a2 = 0.f, a3 = 0.f;
        const float4* h4 = (const float4*)s_h;
        #pragma unroll
        for (int k = 0; k < 16; k += 4) {
            float4 ha = h4[k], hb = h4[k + 1], hc = h4[k + 2], hd = h4[k + 3];
            a0 += w4[k].x     * ha.x + w4[k].y     * ha.y + w4[k].z     * ha.z + w4[k].w     * ha.w;
            a1 += w4[k + 1].x * hb.x + w4[k + 1].y * hb.y + w4[k + 1].z * hb.z + w4[k + 1].w * hb.w;
            a2 += w4[k + 2].x * hc.x + w4[k + 2].y * hc.y + w4[k + 2].z * hc.z + w4[k + 2].w * hc.w;
            a3 += w4[k + 3].x * hd.x + w4[k + 3].y * hd.y + w4[k + 3].z * hd.z + w4[k + 3].w * hd.w;
        }
        float a = ((a0 + a1) + (a2 + a3)) + bh;
        float x = b0j + cof * vcj + (((g0 + g1) + (g2 + g3)) + g4);
        s_a[j] = a;
        s_x[j] = x;
        __syncthreads();

        if (j < 64) {
            float r = sigm(s_x[j] + s_a[j]);
            float z = sigm(s_x[64 + j] + s_a[64 + j]);
            float n = tanh_fast(s_x[128 + j] + r * s_a[128 + j]);
            hi = (1.f - z) * n + z * hi;
            s_h[j] = hi;
            latent[(size_t)(base + t) * 64 + j] = hi;
        }
        __syncthreads();

        g0 = n0; g1 = n1; g2 = n2; g3 = n3; g4 = n4; cof = ncof;
    }
}

// ---------------------------------------------------------------------------
// Kernel 4: readout, one thread per output token.
// ---------------------------------------------------------------------------
__global__ void __launch_bounds__(256) k_final(
    const float* __restrict__ latent, const int* __restrict__ qseq,
    const float* __restrict__ la_W1, const float* __restrict__ la_b1,
    const float* __restrict__ la_W2, const float* __restrict__ la_b2,
    const int* __restrict__ q2c,
    const float* __restrict__ disc, const float* __restrict__ qds,
    const float* __restrict__ wdk, float* __restrict__ out)
{
    int o = blockIdx.x * blockDim.x + threadIdx.x;
    if (o >= BB * (TT - 1)) return;
    int b = o / (TT - 1), t = o - b * (TT - 1);

    const float* lat = latent + (size_t)(b * TT + t) * 64;
    float l[64];
    #pragma unroll
    for (int k4 = 0; k4 < 16; k4++) {
        float4 v = ((const float4*)lat)[k4];
        l[k4 * 4] = v.x; l[k4 * 4 + 1] = v.y; l[k4 * 4 + 2] = v.z; l[k4 * 4 + 3] = v.w;
    }

    int q = qseq[b * TT + t + 1];
    int c0 = q2c[q * 4], c1 = q2c[q * 4 + 1], c2 = q2c[q * 4 + 2], c3 = q2c[q * 4 + 3];

    float u0 = 0.f, u1 = 0.f, u2 = 0.f, u3 = 0.f;
    for (int m = 0; m < 132; m++) {
        float a = la_b1[m];
        const float* w = la_W1 + m * 64;
        #pragma unroll
        for (int k = 0; k < 64; k++) a += w[k] * l[k];
        float hm = fmaxf(a, 0.f);
        u0 += la_W2[c0 * 132 + m] * hm;
        u1 += la_W2[c1 * 132 + m] * hm;
        u2 += la_W2[c2 * 132 + m] * hm;
        u3 += la_W2[c3 * 132 + m] * hm;
    }

    float w0 = wdk[q * 4], w1 = wdk[q * 4 + 1], w2 = wdk[q * 4 + 2], w3 = wdk[q * 4 + 3];
    float us = w0 * sigm(u0 + la_b2[c0]) + w1 * sigm(u1 + la_b2[c1])
             + w2 * sigm(u2 + la_b2[c2]) + w3 * sigm(u3 + la_b2[c3]);
    float qs = qds[q];
    float y = disc[q] * (us - qs) / (qs + 1e-6f);
    out[o] = sigm(y);
}

// ---------------------------------------------------------------------------
extern "C" void kernel_launch(void* const* d_in, const int* in_sizes, int n_in,
                              void* d_out, int out_size, void* d_ws, size_t ws_size,
                              hipStream_t stream)
{
    const float* E_q    = (const float*)d_in[0];
    const float* E_c    = (const float*)d_in[1];
    const float* E_it   = (const float*)d_in[2];
    const float* E_ut   = (const float*)d_in[3];
    const float* E_nh   = (const float*)d_in[4];
    const float* W_fuse = (const float*)d_in[5];
    const float* b_fuse = (const float*)d_in[6];
    const float* W_ih   = (const float*)d_in[7];
    const float* b_ih   = (const float*)d_in[8];
    const float* W_hh   = (const float*)d_in[9];
    const float* b_hh   = (const float*)d_in[10];
    const float* qd_W1  = (const float*)d_in[11];
    const float* qd_b1  = (const float*)d_in[12];
    const float* qd_W2  = (const float*)d_in[13];
    const float* qd_b2  = (const float*)d_in[14];
    const float* la_W1  = (const float*)d_in[15];
    const float* la_b1  = (const float*)d_in[16];
    const float* la_W2  = (const float*)d_in[17];
    const float* la_b2  = (const float*)d_in[18];
    const float* dc_W1  = (const float*)d_in[19];
    const float* dc_b1  = (const float*)d_in[20];
    const float* dc_W2  = (const float*)d_in[21];
    const float* dc_b2  = (const float*)d_in[22];

    int off = (in_sizes[23] == QN * 200) ? 1 : 0;
    const int* qseq  = (const int*)d_in[23 + off];
    const int* cseq  = (const int*)d_in[24 + off];
    const int* itseq = (const int*)d_in[25 + off];
    const int* utseq = (const int*)d_in[26 + off];
    const int* nhseq = (const int*)d_in[27 + off];
    const int* naseq = (const int*)d_in[28 + off];
    const int* q2c   = (const int*)d_in[29 + off];
    const int* q2cm  = (const int*)d_in[30 + off];

    float* ws = (float*)d_ws;
    size_t o = 0;
    float* T_c  = ws + o; o += (size_t)201 * 192;
    float* Tit  = ws + o; o += (size_t)101 * 192;
    float* Tut  = ws + o; o += (size_t)101 * 192;
    float* Tnh  = ws + o; o += (size_t)101 * 192;
    float* Tna  = ws + o; o += (size_t)101 * 192;
    float* b0   = ws + o; o += 192;
    float* vc   = ws + o; o += 192;
    float* Xq   = ws + o; o += (size_t)QN * 192;
    float* disc = ws + o; o += QN;
    float* qds  = ws + o; o += QN;
    float* wdk  = ws + o; o += (size_t)QN * 4;
    float* latent = ws + o; o += (size_t)BB * TT * 64;

    float* outp = (float*)d_out;

    k_tables<<<606, 192, 0, stream>>>(E_c, E_it, E_ut, E_nh, W_fuse, b_fuse, W_ih, b_ih,
                                      T_c, Tit, Tut, Tnh, Tna, b0, vc);
    k_perq<<<QN, 192, 0, stream>>>(E_q, W_ih, qd_W1, qd_b1, qd_W2, qd_b2,
                                   dc_W1, dc_b1, dc_W2, dc_b2, q2c, q2cm, T_c,
                                   Xq, disc, qds, wdk);
    k_gru<<<BB, 192, 0, stream>>>(W_hh, b_hh, Xq, Tit, Tut, Tnh, Tna, b0, vc,
                                  qseq, cseq, itseq, utseq, nhseq, naseq, latent);
    k_final<<<(BB * (TT - 1) + 255) / 256, 256, 0, stream>>>(latent, qseq, la_W1, la_b1,
                                                             la_W2, la_b2, q2c, disc, qds, wdk, outp);
}

// Round 3
// 403.138 us; speedup vs baseline: 1.1704x; 1.0005x over previous
//
#include <hip/hip_runtime.h>

// Problem constants
constexpr int QN  = 10001;   // questions (Q+1)
constexpr int BB  = 512;     // batch
constexpr int TT  = 200;     // seq len

__device__ __forceinline__ float sigm(float x) { return 1.f / (1.f + __expf(-x)); }
__device__ __forceinline__ float tanh_fast(float x) { return 1.f - 2.f / (1.f + __expf(2.f * x)); }

// ---------------------------------------------------------------------------
// Kernel 1: tiny precomputed tables.
//   T_c [201][192]  = W_ih[:,64:128]  @ E_c[r]
//   T_it[101][192]  = W_ih[:,192:256] @ E_it[r]
//   T_ut[101][192]  = W_ih[:,256:320] @ (W_fuse[:,0:64]   @ E_ut[r])
//   T_nh[101][192]  = W_ih[:,256:320] @ (W_fuse[:,64:128] @ E_nh[r])
//   T_na[101][192]  = W_ih[:,256:320] @ (W_fuse[:,128:192]@ E_nh[r])
//   bias0[192]      = b_ih + W_ih[:,256:320] @ b_fuse
//   Vcorr[192]      = rowsum of W_ih[:,128:192]
// ---------------------------------------------------------------------------
__global__ void k_tables(const float* __restrict__ E_c, const float* __restrict__ E_it,
                         const float* __restrict__ E_ut, const float* __restrict__ E_nh,
                         const float* __restrict__ W_fuse, const float* __restrict__ b_fuse,
                         const float* __restrict__ W_ih, const float* __restrict__ b_ih,
                         float* __restrict__ T_c, float* __restrict__ T_it,
                         float* __restrict__ T_ut, float* __restrict__ T_nh, float* __restrict__ T_na,
                         float* __restrict__ bias0, float* __restrict__ Vcorr)
{
    int blk = blockIdx.x, j = threadIdx.x; // 192 threads
    __shared__ float s_e[64];
    __shared__ float s_t[64];

    if (blk < 201) {
        if (j < 64) s_e[j] = E_c[blk * 64 + j];
        __syncthreads();
        float a = 0.f;
        #pragma unroll
        for (int k = 0; k < 64; k++) a += W_ih[j * 320 + 64 + k] * s_e[k];
        T_c[blk * 192 + j] = a;
    } else if (blk < 302) {
        int r = blk - 201;
        if (j < 64) s_e[j] = E_it[r * 64 + j];
        __syncthreads();
        float a = 0.f;
        #pragma unroll
        for (int k = 0; k < 64; k++) a += W_ih[j * 320 + 192 + k] * s_e[k];
        T_it[r * 192 + j] = a;
    } else if (blk < 605) {
        int which = (blk - 302) / 101;
        int r     = (blk - 302) % 101;
        const float* E = (which == 0) ? E_ut : E_nh;
        int fofs = which * 64;
        if (j < 64) s_e[j] = E[r * 64 + j];
        __syncthreads();
        if (j < 64) {
            float a = 0.f;
            #pragma unroll
            for (int d = 0; d < 64; d++) a += W_fuse[j * 192 + fofs + d] * s_e[d];
            s_t[j] = a;
        }
        __syncthreads();
        float a = 0.f;
        #pragma unroll
        for (int e = 0; e < 64; e++) a += W_ih[j * 320 + 256 + e] * s_t[e];
        float* outp = (which == 0) ? T_ut : ((which == 1) ? T_nh : T_na);
        outp[r * 192 + j] = a;
    } else {
        float a = b_ih[j];
        #pragma unroll
        for (int e = 0; e < 64; e++) a += W_ih[j * 320 + 256 + e] * b_fuse[e];
        bias0[j] = a;
        float v = 0.f;
        #pragma unroll
        for (int k = 0; k < 64; k++) v += W_ih[j * 320 + 128 + k];
        Vcorr[j] = v;
    }
}

// ---------------------------------------------------------------------------
// Kernel 2: per-question precompute (10001 blocks x 192 threads).
// ---------------------------------------------------------------------------
__global__ void k_perq(const float* __restrict__ E_q, const float* __restrict__ W_ih,
                       const float* __restrict__ qd_W1, const float* __restrict__ qd_b1,
                       const float* __restrict__ qd_W2, const float* __restrict__ qd_b2,
                       const float* __restrict__ dc_W1, const float* __restrict__ dc_b1,
                       const float* __restrict__ dc_W2, const float* __restrict__ dc_b2,
                       const int* __restrict__ q2c, const int* __restrict__ q2cm,
                       const float* __restrict__ T_c,
                       float* __restrict__ Xq, float* __restrict__ disc,
                       float* __restrict__ qds, float* __restrict__ wdk)
{
    int q = blockIdx.x, tid = threadIdx.x;
    __shared__ float s_qe[64], s_hid[132], s_dch[32], s_raw[4], s_rel[4], s_w[4];
    __shared__ int s_c[4], s_m[4];

    if (tid < 64) s_qe[tid] = E_q[q * 64 + tid];
    if (tid >= 64 && tid < 68) { s_c[tid - 64] = q2c[q * 4 + tid - 64]; s_m[tid - 64] = q2cm[q * 4 + tid - 64]; }
    __syncthreads();

    if (tid < 132) {
        float a = qd_b1[tid];
        const float* w = qd_W1 + tid * 64;
        #pragma unroll
        for (int k = 0; k < 64; k++) a += w[k] * s_qe[k];
        s_hid[tid] = fmaxf(a, 0.f);
    } else if (tid < 164) {
        int i = tid - 132;
        float a = dc_b1[i];
        const float* w = dc_W1 + i * 64;
        #pragma unroll
        for (int k = 0; k < 64; k++) a += w[k] * s_qe[k];
        s_dch[i] = fmaxf(a, 0.f);
    }
    __syncthreads();

    // concept dots: 4 groups of 32 lanes (waves 0,1), shuffle-reduced
    if (tid < 128) {
        int g = tid >> 5, l = tid & 31;
        int c = s_c[g];
        float a = 0.f;
        for (int m = l; m < 132; m += 32) a += qd_W2[c * 132 + m] * s_hid[m];
        #pragma unroll
        for (int off = 16; off; off >>= 1) a += __shfl_xor(a, off, 32);
        if (l == 0) {
            float raw = sigm(a + qd_b2[c]);
            s_raw[g] = raw;
            s_rel[g] = raw * (float)s_m[g];
        }
    } else if (tid < 160) {
        // disc dot on lanes 0..31 of wave 2
        int l = tid - 128;
        float a = dc_W2[l] * s_dch[l];
        #pragma unroll
        for (int off = 16; off; off >>= 1) a += __shfl_xor(a, off, 32);
        if (l == 0) disc[q] = sigm(a + dc_b2[0]) * 10.f;
    }
    __syncthreads();

    if (tid == 0) {
        float sr = s_rel[0] + s_rel[1] + s_rel[2] + s_rel[3] + 1e-6f;
        float qsum = 0.f;
        for (int k = 0; k < 4; k++) {
            s_w[k] = s_rel[k] / sr;
            float wd = 0.f;
            if (s_m[k]) {
                bool dup = false;
                for (int jj = 0; jj < k; jj++)
                    if (s_m[jj] && s_c[jj] == s_c[k]) dup = true;
                if (!dup) { wd = 1.f; qsum += s_raw[k]; }
            }
            wdk[q * 4 + k] = wd;
        }
        qds[q] = qsum;
    }
    __syncthreads();

    {
        float a = 0.f;
        const float* w = W_ih + tid * 320;
        #pragma unroll
        for (int k = 0; k < 64; k++) a += w[k] * s_qe[k];
        #pragma unroll
        for (int k = 0; k < 4; k++) a += s_w[k] * T_c[s_c[k] * 192 + tid];
        Xq[q * 192 + tid] = a;
    }
}

// ---------------------------------------------------------------------------
// Kernel 3: GRU scan, 192 threads (3 waves) per sample. Lane j owns gate-row j
// of W_hh (64 VGPRs, forced resident via min-waves=1), h broadcast via LDS,
// indices staged in LDS, table gathers prefetched one step ahead.
// ---------------------------------------------------------------------------
__global__ void __launch_bounds__(192, 1) k_gru(
    const float* __restrict__ W_hh, const float* __restrict__ b_hh,
    const float* __restrict__ Xq, const float* __restrict__ Tit, const float* __restrict__ Tut,
    const float* __restrict__ Tnh, const float* __restrict__ Tna,
    const float* __restrict__ b0, const float* __restrict__ vc,
    const int* __restrict__ qseq, const int* __restrict__ cseq, const int* __restrict__ itseq,
    const int* __restrict__ utseq, const int* __restrict__ nhseq, const int* __restrict__ naseq,
    float* __restrict__ latent)
{
    int b = blockIdx.x, j = threadIdx.x;
    __shared__ float s_h[64];
    __shared__ float s_a[192];
    __shared__ float s_x[192];
    __shared__ int s_q[TT], s_c[TT], s_it[TT], s_ut[TT], s_nh[TT], s_na[TT];

    const int base = b * TT;
    for (int i = j; i < TT; i += 192) {
        s_q[i]  = qseq[base + i];
        s_c[i]  = cseq[base + i];
        s_it[i] = itseq[base + i];
        s_ut[i] = utseq[base + i];
        s_nh[i] = nhseq[base + i];
        s_na[i] = naseq[base + i];
    }

    // lane j's gate row of W_hh: 16 float4 = 64 VGPRs (resident, no spill)
    float4 w4[16];
    {
        const float4* wp = (const float4*)(W_hh + j * 64);
        #pragma unroll
        for (int k = 0; k < 16; k++) w4[k] = wp[k];
    }
    float bh = b_hh[j], b0j = b0[j], vcj = vc[j];

    if (j < 64) s_h[j] = 0.f;
    float hi = 0.f;
    __syncthreads();  // covers s_idx + s_h init

    // t=0 gathers
    float g0, g1, g2, g3, g4, cof;
    {
        int q = s_q[0], it = s_it[0], ut = s_ut[0], nh = s_nh[0], na = s_na[0];
        cof = (float)s_c[0];
        g0 = Xq[q * 192 + j];  g1 = Tit[it * 192 + j]; g2 = Tut[ut * 192 + j];
        g3 = Tnh[nh * 192 + j]; g4 = Tna[na * 192 + j];
    }

    for (int t = 0; t < TT; t++) {
        // prefetch t+1 gathers (indices from LDS -> no global index chain)
        float n0 = 0.f, n1 = 0.f, n2 = 0.f, n3 = 0.f, n4 = 0.f, ncof = 0.f;
        if (t + 1 < TT) {
            int q = s_q[t + 1], it = s_it[t + 1], ut = s_ut[t + 1];
            int nh = s_nh[t + 1], na = s_na[t + 1];
            ncof = (float)s_c[t + 1];
            n0 = Xq[q * 192 + j];  n1 = Tit[it * 192 + j]; n2 = Tut[ut * 192 + j];
            n3 = Tnh[nh * 192 + j]; n4 = Tna[na * 192 + j];
        }

        // a[j] = W_hh[j,:] . h + b_hh[j]  (h broadcast from LDS, 4 accumulators)
        float a0 = 0.f, a1 = 0.f, a2 = 0.f, a3 = 0.f;
        const float4* h4 = (const float4*)s_h;
        #pragma unroll
        for (int k = 0; k < 16; k += 4) {
            float4 ha = h4[k], hb = h4[k + 1], hc = h4[k + 2], hd = h4[k + 3];
            a0 += w4[k].x     * ha.x + w4[k].y     * ha.y + w4[k].z     * ha.z + w4[k].w     * ha.w;
            a1 += w4[k + 1].x * hb.x + w4[k + 1].y * hb.y + w4[k + 1].z * hb.z + w4[k + 1].w * hb.w;
            a2 += w4[k + 2].x * hc.x + w4[k + 2].y * hc.y + w4[k + 2].z * hc.z + w4[k + 2].w * hc.w;
            a3 += w4[k + 3].x * hd.x + w4[k + 3].y * hd.y + w4[k + 3].z * hd.z + w4[k + 3].w * hd.w;
        }
        float a = ((a0 + a1) + (a2 + a3)) + bh;
        float x = b0j + cof * vcj + (((g0 + g1) + (g2 + g3)) + g4);
        s_a[j] = a;
        s_x[j] = x;
        __syncthreads();

        if (j < 64) {
            float r = sigm(s_x[j] + s_a[j]);
            float z = sigm(s_x[64 + j] + s_a[64 + j]);
            float n = tanh_fast(s_x[128 + j] + r * s_a[128 + j]);
            hi = (1.f - z) * n + z * hi;
            s_h[j] = hi;
            latent[(size_t)(base + t) * 64 + j] = hi;
        }
        __syncthreads();

        g0 = n0; g1 = n1; g2 = n2; g3 = n3; g4 = n4; cof = ncof;
    }
}

// ---------------------------------------------------------------------------
// Kernel 4: readout, one thread per output token. min-waves=2 caps VGPR ~128:
// enough for l[64] + accumulators without spill, keeps 8 waves/CU.
// ---------------------------------------------------------------------------
__global__ void __launch_bounds__(256, 2) k_final(
    const float* __restrict__ latent, const int* __restrict__ qseq,
    const float* __restrict__ la_W1, const float* __restrict__ la_b1,
    const float* __restrict__ la_W2, const float* __restrict__ la_b2,
    const int* __restrict__ q2c,
    const float* __restrict__ disc, const float* __restrict__ qds,
    const float* __restrict__ wdk, float* __restrict__ out)
{
    int o = blockIdx.x * blockDim.x + threadIdx.x;
    if (o >= BB * (TT - 1)) return;
    int b = o / (TT - 1), t = o - b * (TT - 1);

    const float* lat = latent + (size_t)(b * TT + t) * 64;
    float l[64];
    #pragma unroll
    for (int k4 = 0; k4 < 16; k4++) {
        float4 v = ((const float4*)lat)[k4];
        l[k4 * 4] = v.x; l[k4 * 4 + 1] = v.y; l[k4 * 4 + 2] = v.z; l[k4 * 4 + 3] = v.w;
    }

    int q = qseq[b * TT + t + 1];
    int c0 = q2c[q * 4], c1 = q2c[q * 4 + 1], c2 = q2c[q * 4 + 2], c3 = q2c[q * 4 + 3];

    float u0 = 0.f, u1 = 0.f, u2 = 0.f, u3 = 0.f;
    for (int m = 0; m < 132; m++) {
        float a = la_b1[m];
        const float* w = la_W1 + m * 64;
        #pragma unroll
        for (int k = 0; k < 64; k++) a += w[k] * l[k];
        float hm = fmaxf(a, 0.f);
        u0 += la_W2[c0 * 132 + m] * hm;
        u1 += la_W2[c1 * 132 + m] * hm;
        u2 += la_W2[c2 * 132 + m] * hm;
        u3 += la_W2[c3 * 132 + m] * hm;
    }

    float w0 = wdk[q * 4], w1 = wdk[q * 4 + 1], w2 = wdk[q * 4 + 2], w3 = wdk[q * 4 + 3];
    float us = w0 * sigm(u0 + la_b2[c0]) + w1 * sigm(u1 + la_b2[c1])
             + w2 * sigm(u2 + la_b2[c2]) + w3 * sigm(u3 + la_b2[c3]);
    float qs = qds[q];
    float y = disc[q] * (us - qs) / (qs + 1e-6f);
    out[o] = sigm(y);
}

// ---------------------------------------------------------------------------
extern "C" void kernel_launch(void* const* d_in, const int* in_sizes, int n_in,
                              void* d_out, int out_size, void* d_ws, size_t ws_size,
                              hipStream_t stream)
{
    const float* E_q    = (const float*)d_in[0];
    const float* E_c    = (const float*)d_in[1];
    const float* E_it   = (const float*)d_in[2];
    const float* E_ut   = (const float*)d_in[3];
    const float* E_nh   = (const float*)d_in[4];
    const float* W_fuse = (const float*)d_in[5];
    const float* b_fuse = (const float*)d_in[6];
    const float* W_ih   = (const float*)d_in[7];
    const float* b_ih   = (const float*)d_in[8];
    const float* W_hh   = (const float*)d_in[9];
    const float* b_hh   = (const float*)d_in[10];
    const float* qd_W1  = (const float*)d_in[11];
    const float* qd_b1  = (const float*)d_in[12];
    const float* qd_W2  = (const float*)d_in[13];
    const float* qd_b2  = (const float*)d_in[14];
    const float* la_W1  = (const float*)d_in[15];
    const float* la_b1  = (const float*)d_in[16];
    const float* la_W2  = (const float*)d_in[17];
    const float* la_b2  = (const float*)d_in[18];
    const float* dc_W1  = (const float*)d_in[19];
    const float* dc_b1  = (const float*)d_in[20];
    const float* dc_W2  = (const float*)d_in[21];
    const float* dc_b2  = (const float*)d_in[22];

    int off = (in_sizes[23] == QN * 200) ? 1 : 0;
    const int* qseq  = (const int*)d_in[23 + off];
    const int* cseq  = (const int*)d_in[24 + off];
    const int* itseq = (const int*)d_in[25 + off];
    const int* utseq = (const int*)d_in[26 + off];
    const int* nhseq = (const int*)d_in[27 + off];
    const int* naseq = (const int*)d_in[28 + off];
    const int* q2c   = (const int*)d_in[29 + off];
    const int* q2cm  = (const int*)d_in[30 + off];

    float* ws = (float*)d_ws;
    size_t o = 0;
    float* T_c  = ws + o; o += (size_t)201 * 192;
    float* Tit  = ws + o; o += (size_t)101 * 192;
    float* Tut  = ws + o; o += (size_t)101 * 192;
    float* Tnh  = ws + o; o += (size_t)101 * 192;
    float* Tna  = ws + o; o += (size_t)101 * 192;
    float* b0   = ws + o; o += 192;
    float* vc   = ws + o; o += 192;
    float* Xq   = ws + o; o += (size_t)QN * 192;
    float* disc = ws + o; o += QN;
    float* qds  = ws + o; o += QN;
    float* wdk  = ws + o; o += (size_t)QN * 4;
    float* latent = ws + o; o += (size_t)BB * TT * 64;

    float* outp = (float*)d_out;

    k_tables<<<606, 192, 0, stream>>>(E_c, E_it, E_ut, E_nh, W_fuse, b_fuse, W_ih, b_ih,
                                      T_c, Tit, Tut, Tnh, Tna, b0, vc);
    k_perq<<<QN, 192, 0, stream>>>(E_q, W_ih, qd_W1, qd_b1, qd_W2, qd_b2,
                                   dc_W1, dc_b1, dc_W2, dc_b2, q2c, q2cm, T_c,
                                   Xq, disc, qds, wdk);
    k_gru<<<BB, 192, 0, stream>>>(W_hh, b_hh, Xq, Tit, Tut, Tnh, Tna, b0, vc,
                                  qseq, cseq, itseq, utseq, nhseq, naseq, latent);
    k_final<<<(BB * (TT - 1) + 255) / 256, 256, 0, stream>>>(latent, qseq, la_W1, la_b1,
                                                             la_W2, la_b2, q2c, disc, qds, wdk, outp);
}

// Round 4
// 376.793 us; speedup vs baseline: 1.2522x; 1.0699x over previous
//
#include <hip/hip_runtime.h>

// Problem constants
constexpr int QN  = 10001;   // questions (Q+1)
constexpr int BB  = 512;     // batch
constexpr int TT  = 200;     // seq len

__device__ __forceinline__ float sigm(float x) { return 1.f / (1.f + __expf(-x)); }
__device__ __forceinline__ float tanh_fast(float x) { return 1.f - 2.f / (1.f + __expf(2.f * x)); }

// ---------------------------------------------------------------------------
// Kernel 1: tiny precomputed tables.
//   T_c [201][192]  = W_ih[:,64:128]  @ E_c[r]
//   T_it[101][192]  = W_ih[:,192:256] @ E_it[r]
//   T_ut[101][192]  = W_ih[:,256:320] @ (W_fuse[:,0:64]   @ E_ut[r])
//   T_nh[101][192]  = W_ih[:,256:320] @ (W_fuse[:,64:128] @ E_nh[r])
//   T_na[101][192]  = W_ih[:,256:320] @ (W_fuse[:,128:192]@ E_nh[r])
//   bias0[192]      = b_ih + W_ih[:,256:320] @ b_fuse
//   Vcorr[192]      = rowsum of W_ih[:,128:192]
// ---------------------------------------------------------------------------
__global__ void k_tables(const float* __restrict__ E_c, const float* __restrict__ E_it,
                         const float* __restrict__ E_ut, const float* __restrict__ E_nh,
                         const float* __restrict__ W_fuse, const float* __restrict__ b_fuse,
                         const float* __restrict__ W_ih, const float* __restrict__ b_ih,
                         float* __restrict__ T_c, float* __restrict__ T_it,
                         float* __restrict__ T_ut, float* __restrict__ T_nh, float* __restrict__ T_na,
                         float* __restrict__ bias0, float* __restrict__ Vcorr)
{
    int blk = blockIdx.x, j = threadIdx.x; // 192 threads
    __shared__ float s_e[64];
    __shared__ float s_t[64];

    if (blk < 201) {
        if (j < 64) s_e[j] = E_c[blk * 64 + j];
        __syncthreads();
        float a = 0.f;
        #pragma unroll
        for (int k = 0; k < 64; k++) a += W_ih[j * 320 + 64 + k] * s_e[k];
        T_c[blk * 192 + j] = a;
    } else if (blk < 302) {
        int r = blk - 201;
        if (j < 64) s_e[j] = E_it[r * 64 + j];
        __syncthreads();
        float a = 0.f;
        #pragma unroll
        for (int k = 0; k < 64; k++) a += W_ih[j * 320 + 192 + k] * s_e[k];
        T_it[r * 192 + j] = a;
    } else if (blk < 605) {
        int which = (blk - 302) / 101;
        int r     = (blk - 302) % 101;
        const float* E = (which == 0) ? E_ut : E_nh;
        int fofs = which * 64;
        if (j < 64) s_e[j] = E[r * 64 + j];
        __syncthreads();
        if (j < 64) {
            float a = 0.f;
            #pragma unroll
            for (int d = 0; d < 64; d++) a += W_fuse[j * 192 + fofs + d] * s_e[d];
            s_t[j] = a;
        }
        __syncthreads();
        float a = 0.f;
        #pragma unroll
        for (int e = 0; e < 64; e++) a += W_ih[j * 320 + 256 + e] * s_t[e];
        float* outp = (which == 0) ? T_ut : ((which == 1) ? T_nh : T_na);
        outp[r * 192 + j] = a;
    } else {
        float a = b_ih[j];
        #pragma unroll
        for (int e = 0; e < 64; e++) a += W_ih[j * 320 + 256 + e] * b_fuse[e];
        bias0[j] = a;
        float v = 0.f;
        #pragma unroll
        for (int k = 0; k < 64; k++) v += W_ih[j * 320 + 128 + k];
        Vcorr[j] = v;
    }
}

// ---------------------------------------------------------------------------
// Kernel 2: per-question precompute (10001 blocks x 192 threads).
// ---------------------------------------------------------------------------
__global__ void k_perq(const float* __restrict__ E_q, const float* __restrict__ W_ih,
                       const float* __restrict__ qd_W1, const float* __restrict__ qd_b1,
                       const float* __restrict__ qd_W2, const float* __restrict__ qd_b2,
                       const float* __restrict__ dc_W1, const float* __restrict__ dc_b1,
                       const float* __restrict__ dc_W2, const float* __restrict__ dc_b2,
                       const int* __restrict__ q2c, const int* __restrict__ q2cm,
                       const float* __restrict__ T_c,
                       float* __restrict__ Xq, float* __restrict__ disc,
                       float* __restrict__ qds, float* __restrict__ wdk)
{
    int q = blockIdx.x, tid = threadIdx.x;
    __shared__ float s_qe[64], s_hid[132], s_dch[32], s_raw[4], s_rel[4], s_w[4];
    __shared__ int s_c[4], s_m[4];

    if (tid < 64) s_qe[tid] = E_q[q * 64 + tid];
    if (tid >= 64 && tid < 68) { s_c[tid - 64] = q2c[q * 4 + tid - 64]; s_m[tid - 64] = q2cm[q * 4 + tid - 64]; }
    __syncthreads();

    if (tid < 132) {
        float a = qd_b1[tid];
        const float* w = qd_W1 + tid * 64;
        #pragma unroll
        for (int k = 0; k < 64; k++) a += w[k] * s_qe[k];
        s_hid[tid] = fmaxf(a, 0.f);
    } else if (tid < 164) {
        int i = tid - 132;
        float a = dc_b1[i];
        const float* w = dc_W1 + i * 64;
        #pragma unroll
        for (int k = 0; k < 64; k++) a += w[k] * s_qe[k];
        s_dch[i] = fmaxf(a, 0.f);
    }
    __syncthreads();

    // concept dots: 4 groups of 32 lanes (waves 0,1), shuffle-reduced
    if (tid < 128) {
        int g = tid >> 5, l = tid & 31;
        int c = s_c[g];
        float a = 0.f;
        for (int m = l; m < 132; m += 32) a += qd_W2[c * 132 + m] * s_hid[m];
        #pragma unroll
        for (int off = 16; off; off >>= 1) a += __shfl_xor(a, off, 32);
        if (l == 0) {
            float raw = sigm(a + qd_b2[c]);
            s_raw[g] = raw;
            s_rel[g] = raw * (float)s_m[g];
        }
    } else if (tid < 160) {
        // disc dot on lanes 0..31 of wave 2
        int l = tid - 128;
        float a = dc_W2[l] * s_dch[l];
        #pragma unroll
        for (int off = 16; off; off >>= 1) a += __shfl_xor(a, off, 32);
        if (l == 0) disc[q] = sigm(a + dc_b2[0]) * 10.f;
    }
    __syncthreads();

    if (tid == 0) {
        float sr = s_rel[0] + s_rel[1] + s_rel[2] + s_rel[3] + 1e-6f;
        float qsum = 0.f;
        for (int k = 0; k < 4; k++) {
            s_w[k] = s_rel[k] / sr;
            float wd = 0.f;
            if (s_m[k]) {
                bool dup = false;
                for (int jj = 0; jj < k; jj++)
                    if (s_m[jj] && s_c[jj] == s_c[k]) dup = true;
                if (!dup) { wd = 1.f; qsum += s_raw[k]; }
            }
            wdk[q * 4 + k] = wd;
        }
        qds[q] = qsum;
    }
    __syncthreads();

    {
        float a = 0.f;
        const float* w = W_ih + tid * 320;
        #pragma unroll
        for (int k = 0; k < 64; k++) a += w[k] * s_qe[k];
        #pragma unroll
        for (int k = 0; k < 4; k++) a += s_w[k] * T_c[s_c[k] * 192 + tid];
        Xq[q * 192 + tid] = a;
    }
}

// ---------------------------------------------------------------------------
// Kernel 3: GRU scan, 192 threads (3 waves) per sample. Lane j owns gate-row j
// of W_hh (64 VGPRs). The empty asm below makes the loaded weights opaque so
// the compiler CANNOT sink/rematerialize the loads into the loop (rounds 2-3:
// allocator chose VGPR=56 and re-loaded 16x dwordx4 from L2 every step).
// h broadcast via LDS, indices staged in LDS, gathers prefetched 1 step ahead.
// ---------------------------------------------------------------------------
__global__ void __launch_bounds__(192, 1) k_gru(
    const float* __restrict__ W_hh, const float* __restrict__ b_hh,
    const float* __restrict__ Xq, const float* __restrict__ Tit, const float* __restrict__ Tut,
    const float* __restrict__ Tnh, const float* __restrict__ Tna,
    const float* __restrict__ b0, const float* __restrict__ vc,
    const int* __restrict__ qseq, const int* __restrict__ cseq, const int* __restrict__ itseq,
    const int* __restrict__ utseq, const int* __restrict__ nhseq, const int* __restrict__ naseq,
    float* __restrict__ latent)
{
    int b = blockIdx.x, j = threadIdx.x;
    __shared__ float s_h[64];
    __shared__ float s_a[192];
    __shared__ float s_x[192];
    __shared__ int s_q[TT], s_c[TT], s_it[TT], s_ut[TT], s_nh[TT], s_na[TT];

    const int base = b * TT;
    for (int i = j; i < TT; i += 192) {
        s_q[i]  = qseq[base + i];
        s_c[i]  = cseq[base + i];
        s_it[i] = itseq[base + i];
        s_ut[i] = utseq[base + i];
        s_nh[i] = nhseq[base + i];
        s_na[i] = naseq[base + i];
    }

    // lane j's gate row of W_hh: 16 float4 = 64 VGPRs, pinned resident.
    float4 w4[16];
    {
        const float4* wp = (const float4*)(W_hh + j * 64);
        #pragma unroll
        for (int k = 0; k < 16; k++) w4[k] = wp[k];
    }
    // Optimization barrier: outputs of asm are not rematerializable, forcing
    // the 64 weight values to stay live in VGPRs across the whole scan.
    #pragma unroll
    for (int k = 0; k < 16; k++)
        asm volatile("" : "+v"(w4[k].x), "+v"(w4[k].y), "+v"(w4[k].z), "+v"(w4[k].w));

    float bh = b_hh[j], b0j = b0[j], vcj = vc[j];

    if (j < 64) s_h[j] = 0.f;
    float hi = 0.f;
    __syncthreads();  // covers s_idx + s_h init

    // t=0 gathers
    float g0, g1, g2, g3, g4, cof;
    {
        int q = s_q[0], it = s_it[0], ut = s_ut[0], nh = s_nh[0], na = s_na[0];
        cof = (float)s_c[0];
        g0 = Xq[q * 192 + j];  g1 = Tit[it * 192 + j]; g2 = Tut[ut * 192 + j];
        g3 = Tnh[nh * 192 + j]; g4 = Tna[na * 192 + j];
    }

    for (int t = 0; t < TT; t++) {
        // prefetch t+1 gathers (indices from LDS -> no global index chain)
        float n0 = 0.f, n1 = 0.f, n2 = 0.f, n3 = 0.f, n4 = 0.f, ncof = 0.f;
        if (t + 1 < TT) {
            int q = s_q[t + 1], it = s_it[t + 1], ut = s_ut[t + 1];
            int nh = s_nh[t + 1], na = s_na[t + 1];
            ncof = (float)s_c[t + 1];
            n0 = Xq[q * 192 + j];  n1 = Tit[it * 192 + j]; n2 = Tut[ut * 192 + j];
            n3 = Tnh[nh * 192 + j]; n4 = Tna[na * 192 + j];
        }

        // a[j] = W_hh[j,:] . h + b_hh[j]  (h broadcast from LDS, 4 accumulators)
        float a0 = 0.f, a1 = 0.f, a2 = 0.f, a3 = 0.f;
        const float4* h4 = (const float4*)s_h;
        #pragma unroll
        for (int k = 0; k < 16; k += 4) {
            float4 ha = h4[k], hb = h4[k + 1], hc = h4[k + 2], hd = h4[k + 3];
            a0 += w4[k].x     * ha.x + w4[k].y     * ha.y + w4[k].z     * ha.z + w4[k].w     * ha.w;
            a1 += w4[k + 1].x * hb.x + w4[k + 1].y * hb.y + w4[k + 1].z * hb.z + w4[k + 1].w * hb.w;
            a2 += w4[k + 2].x * hc.x + w4[k + 2].y * hc.y + w4[k + 2].z * hc.z + w4[k + 2].w * hc.w;
            a3 += w4[k + 3].x * hd.x + w4[k + 3].y * hd.y + w4[k + 3].z * hd.z + w4[k + 3].w * hd.w;
        }
        float a = ((a0 + a1) + (a2 + a3)) + bh;
        float x = b0j + cof * vcj + (((g0 + g1) + (g2 + g3)) + g4);
        s_a[j] = a;
        s_x[j] = x;
        __syncthreads();

        if (j < 64) {
            float r = sigm(s_x[j] + s_a[j]);
            float z = sigm(s_x[64 + j] + s_a[64 + j]);
            float n = tanh_fast(s_x[128 + j] + r * s_a[128 + j]);
            hi = (1.f - z) * n + z * hi;
            s_h[j] = hi;
            latent[(size_t)(base + t) * 64 + j] = hi;
        }
        __syncthreads();

        g0 = n0; g1 = n1; g2 = n2; g3 = n3; g4 = n4; cof = ncof;
    }
}

// ---------------------------------------------------------------------------
// Kernel 4: readout, one thread per output token. min-waves=2 caps VGPR ~128:
// enough for l[64] + accumulators without spill, keeps 8 waves/CU.
// ---------------------------------------------------------------------------
__global__ void __launch_bounds__(256, 2) k_final(
    const float* __restrict__ latent, const int* __restrict__ qseq,
    const float* __restrict__ la_W1, const float* __restrict__ la_b1,
    const float* __restrict__ la_W2, const float* __restrict__ la_b2,
    const int* __restrict__ q2c,
    const float* __restrict__ disc, const float* __restrict__ qds,
    const float* __restrict__ wdk, float* __restrict__ out)
{
    int o = blockIdx.x * blockDim.x + threadIdx.x;
    if (o >= BB * (TT - 1)) return;
    int b = o / (TT - 1), t = o - b * (TT - 1);

    const float* lat = latent + (size_t)(b * TT + t) * 64;
    float l[64];
    #pragma unroll
    for (int k4 = 0; k4 < 16; k4++) {
        float4 v = ((const float4*)lat)[k4];
        l[k4 * 4] = v.x; l[k4 * 4 + 1] = v.y; l[k4 * 4 + 2] = v.z; l[k4 * 4 + 3] = v.w;
    }

    int q = qseq[b * TT + t + 1];
    int c0 = q2c[q * 4], c1 = q2c[q * 4 + 1], c2 = q2c[q * 4 + 2], c3 = q2c[q * 4 + 3];

    float u0 = 0.f, u1 = 0.f, u2 = 0.f, u3 = 0.f;
    for (int m = 0; m < 132; m++) {
        float a = la_b1[m];
        const float* w = la_W1 + m * 64;
        #pragma unroll
        for (int k = 0; k < 64; k++) a += w[k] * l[k];
        float hm = fmaxf(a, 0.f);
        u0 += la_W2[c0 * 132 + m] * hm;
        u1 += la_W2[c1 * 132 + m] * hm;
        u2 += la_W2[c2 * 132 + m] * hm;
        u3 += la_W2[c3 * 132 + m] * hm;
    }

    float w0 = wdk[q * 4], w1 = wdk[q * 4 + 1], w2 = wdk[q * 4 + 2], w3 = wdk[q * 4 + 3];
    float us = w0 * sigm(u0 + la_b2[c0]) + w1 * sigm(u1 + la_b2[c1])
             + w2 * sigm(u2 + la_b2[c2]) + w3 * sigm(u3 + la_b2[c3]);
    float qs = qds[q];
    float y = disc[q] * (us - qs) / (qs + 1e-6f);
    out[o] = sigm(y);
}

// ---------------------------------------------------------------------------
extern "C" void kernel_launch(void* const* d_in, const int* in_sizes, int n_in,
                              void* d_out, int out_size, void* d_ws, size_t ws_size,
                              hipStream_t stream)
{
    const float* E_q    = (const float*)d_in[0];
    const float* E_c    = (const float*)d_in[1];
    const float* E_it   = (const float*)d_in[2];
    const float* E_ut   = (const float*)d_in[3];
    const float* E_nh   = (const float*)d_in[4];
    const float* W_fuse = (const float*)d_in[5];
    const float* b_fuse = (const float*)d_in[6];
    const float* W_ih   = (const float*)d_in[7];
    const float* b_ih   = (const float*)d_in[8];
    const float* W_hh   = (const float*)d_in[9];
    const float* b_hh   = (const float*)d_in[10];
    const float* qd_W1  = (const float*)d_in[11];
    const float* qd_b1  = (const float*)d_in[12];
    const float* qd_W2  = (const float*)d_in[13];
    const float* qd_b2  = (const float*)d_in[14];
    const float* la_W1  = (const float*)d_in[15];
    const float* la_b1  = (const float*)d_in[16];
    const float* la_W2  = (const float*)d_in[17];
    const float* la_b2  = (const float*)d_in[18];
    const float* dc_W1  = (const float*)d_in[19];
    const float* dc_b1  = (const float*)d_in[20];
    const float* dc_W2  = (const float*)d_in[21];
    const float* dc_b2  = (const float*)d_in[22];

    int off = (in_sizes[23] == QN * 200) ? 1 : 0;
    const int* qseq  = (const int*)d_in[23 + off];
    const int* cseq  = (const int*)d_in[24 + off];
    const int* itseq = (const int*)d_in[25 + off];
    const int* utseq = (const int*)d_in[26 + off];
    const int* nhseq = (const int*)d_in[27 + off];
    const int* naseq = (const int*)d_in[28 + off];
    const int* q2c   = (const int*)d_in[29 + off];
    const int* q2cm  = (const int*)d_in[30 + off];

    float* ws = (float*)d_ws;
    size_t o = 0;
    float* T_c  = ws + o; o += (size_t)201 * 192;
    float* Tit  = ws + o; o += (size_t)101 * 192;
    float* Tut  = ws + o; o += (size_t)101 * 192;
    float* Tnh  = ws + o; o += (size_t)101 * 192;
    float* Tna  = ws + o; o += (size_t)101 * 192;
    float* b0   = ws + o; o += 192;
    float* vc   = ws + o; o += 192;
    float* Xq   = ws + o; o += (size_t)QN * 192;
    float* disc = ws + o; o += QN;
    float* qds  = ws + o; o += QN;
    float* wdk  = ws + o; o += (size_t)QN * 4;
    float* latent = ws + o; o += (size_t)BB * TT * 64;

    float* outp = (float*)d_out;

    k_tables<<<606, 192, 0, stream>>>(E_c, E_it, E_ut, E_nh, W_fuse, b_fuse, W_ih, b_ih,
                                      T_c, Tit, Tut, Tnh, Tna, b0, vc);
    k_perq<<<QN, 192, 0, stream>>>(E_q, W_ih, qd_W1, qd_b1, qd_W2, qd_b2,
                                   dc_W1, dc_b1, dc_W2, dc_b2, q2c, q2cm, T_c,
                                   Xq, disc, qds, wdk);
    k_gru<<<BB, 192, 0, stream>>>(W_hh, b_hh, Xq, Tit, Tut, Tnh, Tna, b0, vc,
                                  qseq, cseq, itseq, utseq, nhseq, naseq, latent);
    k_final<<<(BB * (TT - 1) + 255) / 256, 256, 0, stream>>>(latent, qseq, la_W1, la_b1,
                                                             la_W2, la_b2, q2c, disc, qds, wdk, outp);
}